// Round 12
// baseline (85.851 us; speedup 1.0000x reference)
//
#include <hip/hip_runtime.h>
#include <cstdint>

// Ball query: B=8, N=4096, radius=0.2, nsample=32. Queries == sources.
// Output int32 (B,N,32): first 32 in-radius indices ascending, padded with
// the first match.
//
// NUMERICS (LOCKED, R8-verified absmax=0): expansion form f32,
//   sq  = (x*x + y*y) + z*z              -- plain, no FMA
//   dot = fma(qz,sz, fma(qy,sy, qx*sx))  -- FMA, K ascending
//   d2  = (sqq + sqs) - (dot + dot)
//   match = d2 < 0.04f
// All in inline asm -- immune to -ffast-math/contract. DO NOT CHANGE.
//
// R12 perf: R11 (~35us kernel) still latency/overhead-bound. This round:
// 512-thread blocks + full 64KiB tile (2 blocks/CU -> 16 waves/CU, same
// occupancy as R11 but 1 barrier, no restage) and an 8-query ACTIVE-MASK
// cascade: every ds_read_b128 feeds all still-active queries of the wave
// (uniform branches; per-chunk deactivation at found>=32). LDS rounds/wave
// = max(scan over 8 queries)/64 instead of pair-sum -- ~2.7x fewer.

#define BQ_N   4096
#define BQ_B   8
#define BQ_NS  32
#define BQ_R2  0.04f

__device__ __forceinline__ float sq_plain(float x, float y, float z) {
    float r, t;
    asm("v_mul_f32 %0, %2, %2\n\t"
        "v_mul_f32 %1, %3, %3\n\t"
        "v_add_f32 %0, %0, %1\n\t"
        "v_mul_f32 %1, %4, %4\n\t"
        "v_add_f32 %0, %0, %1"
        : "=&v"(r), "=&v"(t)
        : "v"(x), "v"(y), "v"(z));
    return r;
}

__device__ __forceinline__ float d2_mixed(float qx, float qy, float qz, float sqq,
                                          float sx, float sy, float sz, float sqs) {
    float r, t;
    asm("v_mul_f32 %0, %2, %5\n\t"     // qx*sx
        "v_fma_f32 %0, %3, %6, %0\n\t" // + qy*sy (fused)
        "v_fma_f32 %0, %4, %7, %0\n\t" // + qz*sz (fused) = dot
        "v_add_f32 %0, %0, %0\n\t"     // 2*dot (exact)
        "v_add_f32 %1, %8, %9\n\t"     // sqq + sqs
        "v_sub_f32 %0, %1, %0"         // d2
        : "=&v"(r), "=&v"(t)
        : "v"(qx), "v"(qy), "v"(qz), "v"(sx), "v"(sy), "v"(sz),
          "v"(sqq), "v"(sqs));
    return r;
}

__device__ __forceinline__ void emit_query(int* orow, int lane, uint64_t word) {
    const int cnt = __popcll(word);
    int incl = cnt;
    #pragma unroll
    for (int off = 1; off < 64; off <<= 1) {
        const int t = __shfl_up(incl, off);
        if (lane >= off) incl += t;
    }
    const int pre   = incl - cnt;
    const int total = __shfl(incl, 63);

    int first;
    const uint64_t nz = __ballot(word != 0ull);
    if (nz == 0ull) {
        first = BQ_N;   // defensive; self-match (d2_self == -0 or ~0) -> unreachable
    } else {
        const int fl = __builtin_ctzll(nz);
        const uint64_t fw = __shfl(word, fl);
        first = (fl << 6) + __builtin_ctzll(fw);
    }

    uint64_t w = word;
    int pos = pre;
    while (w != 0ull && pos < BQ_NS) {
        const int bit = __builtin_ctzll(w);
        orow[pos] = (lane << 6) + bit;
        w &= (w - 1);
        ++pos;
    }
    // vectorized padding: lanes [total, 32) store `first`
    if (lane >= total && lane < BQ_NS) orow[lane] = first;
}

__global__ __launch_bounds__(512, 4)
void ball_query_kernel(const float* __restrict__ xyz, int* __restrict__ out)
{
    __shared__ float4 pts[BQ_N];   // 64 KiB -> 2 blocks/CU, 16 waves/CU

    const int b     = blockIdx.x >> 6;         // 64 blocks per batch
    const int qbase = (blockIdx.x & 63) << 6;  // 64 queries per block
    const float* __restrict__ src = xyz + (size_t)b * BQ_N * 3;
    const int lane = threadIdx.x & 63;
    const int wid  = threadIdx.x >> 6;         // 0..7
    int* __restrict__ outb = out + (size_t)(b * BQ_N) * BQ_NS;

    // Single stage of the full 4096-point set.
    for (int j = threadIdx.x; j < BQ_N; j += 512) {
        const float x = src[3 * j + 0];
        const float y = src[3 * j + 1];
        const float z = src[3 * j + 2];
        pts[j] = make_float4(x, y, z, sq_plain(x, y, z));
    }
    __syncthreads();

    // Wave's 8 queries (broadcast LDS reads; values identical to staging).
    float4 Q[8];
    #pragma unroll
    for (int j = 0; j < 8; ++j) Q[j] = pts[qbase + (wid << 3) + j];

    uint64_t W[8] = {0, 0, 0, 0, 0, 0, 0, 0};
    int      F[8] = {0, 0, 0, 0, 0, 0, 0, 0};
    unsigned active = 0xFFu;   // wave-uniform (F from ballot popcounts)

    // Active-mask cascade: 16 chunks x 4 rounds x 64 points. Each
    // ds_read_b128 feeds all still-active queries; per-chunk deactivation.
    #pragma unroll 1
    for (int c = 0; c < 16 && active; ++c) {
        #pragma unroll
        for (int u = 0; u < 4; ++u) {
            const int k = (c << 2) + u;
            const float4 s = pts[(k << 6) + lane];
            #pragma unroll
            for (int i = 0; i < 8; ++i) {
                if (active & (1u << i)) {          // uniform branch
                    const float d2 = d2_mixed(Q[i].x, Q[i].y, Q[i].z, Q[i].w,
                                              s.x, s.y, s.z, s.w);
                    const uint64_t bal = __ballot(d2 < BQ_R2);
                    if (lane == k) W[i] = bal;
                    F[i] += (int)__popcll(bal);
                }
            }
        }
        #pragma unroll
        for (int i = 0; i < 8; ++i)
            if (F[i] >= BQ_NS) active &= ~(1u << i);
    }

    #pragma unroll 1
    for (int j = 0; j < 8; ++j) {
        const int m = qbase + (wid << 3) + j;
        emit_query(outb + (size_t)m * BQ_NS, lane, W[j]);
    }
}

extern "C" void kernel_launch(void* const* d_in, const int* in_sizes, int n_in,
                              void* d_out, int out_size, void* d_ws, size_t ws_size,
                              hipStream_t stream)
{
    const float* xyz = (const float*)d_in[0];   // (8, 4096, 3) f32; d_in[1] unused
    int* out = (int*)d_out;                     // (8, 4096, 32) int32
    hipLaunchKernelGGL(ball_query_kernel, dim3(BQ_B * 64), dim3(512), 0, stream,
                       xyz, out);
}

// Round 13
// 84.304 us; speedup vs baseline: 1.0184x; 1.0184x over previous
//
#include <hip/hip_runtime.h>
#include <cstdint>

// Ball query: B=8, N=4096, radius=0.2, nsample=32. Queries == sources.
// Output int32 (B,N,32): first 32 in-radius indices ascending, padded with
// the first match.
//
// NUMERICS (LOCKED, R8-verified absmax=0): expansion form f32,
//   sq  = (x*x + y*y) + z*z              -- plain, no FMA
//   dot = fma(qz,sz, fma(qy,sy, qx*sx))  -- FMA, K ascending
//   d2  = (sqq + sqs) - (dot + dot)
//   match = d2 < 0.04f
// Inline asm, same opcode sequence (query operands now from SGPRs -- operand
// bank does not change rounding). DO NOT CHANGE the op sequence.
//
// R13 perf: R10-R12 latency-bound at <=16 waves/CU (VALUBusy ~45%; VALU
// floor ~10us, LDS ~9us vs 35us wall). This round: 512-thr blocks x 32KiB
// half-tile restage -> 4 blocks/CU x 8 waves = 32 waves/CU (occupancy max),
// queries in SGPRs + 4 queries/wave so state fits the 64-VGPR/wave cap
// (__launch_bounds__(512,8)). Active-mask scan, 256-pt chunk early-exit.

#define BQ_N    4096
#define BQ_HALF 2048
#define BQ_B    8
#define BQ_NS   32
#define BQ_R2   0.04f

__device__ __forceinline__ float sq_plain(float x, float y, float z) {
    float r, t;
    asm("v_mul_f32 %0, %2, %2\n\t"
        "v_mul_f32 %1, %3, %3\n\t"
        "v_add_f32 %0, %0, %1\n\t"
        "v_mul_f32 %1, %4, %4\n\t"
        "v_add_f32 %0, %0, %1"
        : "=&v"(r), "=&v"(t)
        : "v"(x), "v"(y), "v"(z));
    return r;
}

// Query components come from SGPRs (wave-uniform): each VALU op reads
// exactly one SGPR (legal). Identical opcodes/order as the verified R8 asm.
__device__ __forceinline__ float d2_mixed_s(float qx, float qy, float qz,
                                            float sqq,
                                            float sx, float sy, float sz,
                                            float sqs) {
    float r, t;
    asm("v_mul_f32 %0, %2, %5\n\t"     // qx*sx
        "v_fma_f32 %0, %3, %6, %0\n\t" // + qy*sy (fused)
        "v_fma_f32 %0, %4, %7, %0\n\t" // + qz*sz (fused) = dot
        "v_add_f32 %0, %0, %0\n\t"     // 2*dot (exact)
        "v_add_f32 %1, %8, %9\n\t"     // sqq + sqs
        "v_sub_f32 %0, %1, %0"         // d2
        : "=&v"(r), "=&v"(t)
        : "s"(qx), "s"(qy), "s"(qz), "v"(sx), "v"(sy), "v"(sz),
          "s"(sqq), "v"(sqs));
    return r;
}

__device__ __forceinline__ float rfl(float v) {
    return __int_as_float(__builtin_amdgcn_readfirstlane(__float_as_int(v)));
}

__device__ __forceinline__ void emit_query(int* orow, int lane, uint64_t word) {
    const int cnt = __popcll(word);
    int incl = cnt;
    #pragma unroll
    for (int off = 1; off < 64; off <<= 1) {
        const int t = __shfl_up(incl, off);
        if (lane >= off) incl += t;
    }
    const int pre   = incl - cnt;
    const int total = __shfl(incl, 63);

    int first;
    const uint64_t nz = __ballot(word != 0ull);
    if (nz == 0ull) {
        first = BQ_N;   // defensive; self-match makes this unreachable
    } else {
        const int fl = __builtin_ctzll(nz);
        const uint64_t fw = __shfl(word, fl);
        first = (fl << 6) + __builtin_ctzll(fw);
    }

    uint64_t w = word;
    int pos = pre;
    while (w != 0ull && pos < BQ_NS) {
        const int bit = __builtin_ctzll(w);
        orow[pos] = (lane << 6) + bit;
        w &= (w - 1);
        ++pos;
    }
    // vectorized padding: lanes [total, 32) store `first`
    if (lane >= total && lane < BQ_NS) orow[lane] = first;
}

__global__ __launch_bounds__(512, 8)
void ball_query_kernel(const float* __restrict__ xyz, int* __restrict__ out)
{
    __shared__ float4 pts[BQ_HALF];   // 32 KiB -> 4 blocks/CU, 32 waves/CU

    const int b     = blockIdx.x >> 7;          // 128 blocks per batch
    const int qbase = (blockIdx.x & 127) << 5;  // 32 queries per block
    const float* __restrict__ src = xyz + (size_t)b * BQ_N * 3;
    const int lane = threadIdx.x & 63;
    const int wid  = threadIdx.x >> 6;          // 0..7
    int* __restrict__ outb = out + (size_t)(b * BQ_N) * BQ_NS;

    // Wave's 4 queries -> SGPRs (all lanes read the same address; values
    // are wave-uniform, readfirstlane pins them to scalar registers).
    float qx[4], qy[4], qz[4], qw[4];
    #pragma unroll
    for (int j = 0; j < 4; ++j) {
        const int m = qbase + (wid << 2) + j;
        const float x = src[3 * m + 0];
        const float y = src[3 * m + 1];
        const float z = src[3 * m + 2];
        const float w = sq_plain(x, y, z);
        qx[j] = rfl(x); qy[j] = rfl(y); qz[j] = rfl(z); qw[j] = rfl(w);
    }

    // Stage phase-A half (points 0..2047).
    for (int j = threadIdx.x; j < BQ_HALF; j += 512) {
        const float x = src[3 * j + 0];
        const float y = src[3 * j + 1];
        const float z = src[3 * j + 2];
        pts[j] = make_float4(x, y, z, sq_plain(x, y, z));
    }
    __syncthreads();

    uint64_t W[4] = {0, 0, 0, 0};
    int      F[4] = {0, 0, 0, 0};
    unsigned active = 0xFu;   // wave-uniform

    // Phase A: 8 chunks x 4 rounds x 64 pts (k = 0..31).
    #pragma unroll 1
    for (int c = 0; c < 8 && active; ++c) {
        #pragma unroll
        for (int u = 0; u < 4; ++u) {
            const int k = (c << 2) + u;
            const float4 s = pts[(k << 6) + lane];
            #pragma unroll
            for (int i = 0; i < 4; ++i) {
                if (active & (1u << i)) {          // uniform branch
                    const float d2 = d2_mixed_s(qx[i], qy[i], qz[i], qw[i],
                                                s.x, s.y, s.z, s.w);
                    const uint64_t bal = __ballot(d2 < BQ_R2);
                    if (lane == k) W[i] = bal;
                    F[i] += (int)__popcll(bal);
                }
            }
        }
        #pragma unroll
        for (int i = 0; i < 4; ++i)
            if (F[i] >= BQ_NS) active &= ~(1u << i);
    }

    // Restage phase-B half (points 2048..4095). All waves hit barriers.
    __syncthreads();
    for (int j = threadIdx.x; j < BQ_HALF; j += 512) {
        const int g = BQ_HALF + j;
        const float x = src[3 * g + 0];
        const float y = src[3 * g + 1];
        const float z = src[3 * g + 2];
        pts[j] = make_float4(x, y, z, sq_plain(x, y, z));
    }
    __syncthreads();

    // Phase B: 8 chunks, k2 = 32..63.
    #pragma unroll 1
    for (int c = 0; c < 8 && active; ++c) {
        #pragma unroll
        for (int u = 0; u < 4; ++u) {
            const int k  = (c << 2) + u;
            const int k2 = 32 + k;
            const float4 s = pts[(k << 6) + lane];
            #pragma unroll
            for (int i = 0; i < 4; ++i) {
                if (active & (1u << i)) {          // uniform branch
                    const float d2 = d2_mixed_s(qx[i], qy[i], qz[i], qw[i],
                                                s.x, s.y, s.z, s.w);
                    const uint64_t bal = __ballot(d2 < BQ_R2);
                    if (lane == k2) W[i] = bal;
                    F[i] += (int)__popcll(bal);
                }
            }
        }
        #pragma unroll
        for (int i = 0; i < 4; ++i)
            if (F[i] >= BQ_NS) active &= ~(1u << i);
    }

    #pragma unroll 1
    for (int j = 0; j < 4; ++j) {
        const int m = qbase + (wid << 2) + j;
        emit_query(outb + (size_t)m * BQ_NS, lane, W[j]);
    }
}

extern "C" void kernel_launch(void* const* d_in, const int* in_sizes, int n_in,
                              void* d_out, int out_size, void* d_ws, size_t ws_size,
                              hipStream_t stream)
{
    const float* xyz = (const float*)d_in[0];   // (8, 4096, 3) f32; d_in[1] unused
    int* out = (int*)d_out;                     // (8, 4096, 32) int32
    hipLaunchKernelGGL(ball_query_kernel, dim3(1024), dim3(512), 0, stream,
                       xyz, out);
}